// Round 1
// baseline (28902.264 us; speedup 1.0000x reference)
//
#include <hip/hip_runtime.h>
#include <cmath>

#define HID    1024
#define VOCAB  32000
#define BATCH  64
#define TLEN   128
#define FC_NCB 250              // 32000 / 128 cols per block

// workspace layout (float units)
#define X2T_OFF  0                          // [2048][64]  (x rows 0..1023, h rows 1024..2047)
#define GBUF_OFF (2048*64)                  // [8][64][4096]
#define PV_OFF   (GBUF_OFF + 8*64*4096)     // [64][250] float
#define PI_OFF   (PV_OFF + 64*FC_NCB)       // [64][250] int

// -------------------------------------------------------------------------
// prep: finalize argmax of previous step, gather embedding into X2T (k-major)
// grid 64 (one block per batch row), 256 threads
__global__ __launch_bounds__(256) void k_prep(
    const float* __restrict__ enc, const int* __restrict__ tt,
    const float* __restrict__ emb, float* __restrict__ X2T,
    const float* __restrict__ pv, const int* __restrict__ pi, int t) {
  const int r = blockIdx.x;
  const int tid = threadIdx.x;
  __shared__ int s_tok;
  __shared__ float red_v[256];
  __shared__ int red_i[256];
  if (t == 0) {
    if (tid == 0) s_tok = tt[r * TLEN];   // target_tokens[r][0]
  } else {
    float v = -INFINITY; int idx = 0x7fffffff;
    if (tid < FC_NCB) { v = pv[r * FC_NCB + tid]; idx = pi[r * FC_NCB + tid]; }
    red_v[tid] = v; red_i[tid] = idx;
    __syncthreads();
    for (int s = 128; s > 0; s >>= 1) {
      if (tid < s) {
        float v2 = red_v[tid + s]; int i2 = red_i[tid + s];
        if (v2 > red_v[tid] || (v2 == red_v[tid] && i2 < red_i[tid])) {
          red_v[tid] = v2; red_i[tid] = i2;
        }
      }
      __syncthreads();
    }
    if (tid == 0) s_tok = red_i[0];
  }
  __syncthreads();
  const int tok = s_tok;
  for (int k = tid; k < HID; k += 256)
    X2T[(size_t)k * 64 + r] = emb[(size_t)tok * HID + k];
  if (t == 0) {
    for (int k = tid; k < HID; k += 256)
      X2T[(size_t)(HID + k) * 64 + r] = enc[r * HID + k];
  }
}

// -------------------------------------------------------------------------
// gates GEMM: [64 x 2048] @ [2048 x 4096(synthetic)] with K split into 8 slices
// synthetic cols: [0,1024)=sr, [1024,2048)=sz, [2048,3072)=inn, [3072,4096)=hn
// grid 256 = 32 colblocks * 8 slices, 256 threads (4 waves: 2 rowhalf x 2 colhalf)
__global__ __launch_bounds__(256) void k_gates(
    const float* __restrict__ w_ih, const float* __restrict__ w_hh,
    const float* __restrict__ X2T, float* __restrict__ gbuf) {
  const int cb = blockIdx.x & 31;
  const int s  = blockIdx.x >> 5;
  const int g  = cb >> 3;                  // gate group of this col-block
  if (g == 2 && s >= 4) return;            // inn only uses x (slices 0-3)
  if (g == 3 && s < 4) return;             // hn only uses h (slices 4-7)
  const int tid  = threadIdx.x;
  const int w    = __builtin_amdgcn_readfirstlane(tid >> 6);
  const int lane = tid & 63;
  const int r0   = (w >> 1) * 32;
  const int cc   = cb * 128 + (w & 1) * 64 + lane;
  const int j    = cc & 1023;
  const float* Bmat; int kk0;
  if (s < 4) { Bmat = w_ih; kk0 = s * 256; }
  else       { Bmat = w_hh; kk0 = (s - 4) * 256; }
  int brow;
  if (g == 0) brow = j;
  else if (g == 1) brow = 1024 + j;
  else brow = 2048 + j;
  const float* Bp = Bmat + (size_t)brow * HID + kk0;
  const float* Ap = X2T + (size_t)(s * 256) * 64 + r0;   // synthetic-k base
  float acc[32];
  #pragma unroll
  for (int i = 0; i < 32; i++) acc[i] = 0.f;
  for (int k = 0; k < 256; k += 4) {
    float4 b = *(const float4*)(Bp + k);
    #pragma unroll
    for (int kk = 0; kk < 4; kk++) {
      const float bk = (&b.x)[kk];
      const float* a = Ap + (size_t)(k + kk) * 64;
      #pragma unroll
      for (int i = 0; i < 32; i++) acc[i] = fmaf(a[i], bk, acc[i]);
    }
  }
  float* C = gbuf + (size_t)s * (64 * 4096) + cc;
  #pragma unroll
  for (int i = 0; i < 32; i++) C[(size_t)(r0 + i) * 4096] = acc[i];
}

// -------------------------------------------------------------------------
// combine: sum K-slices, biases, GRU nonlinearity, update h in X2T rows 1024..
// grid 256 x 256 = 65536 threads = 64 rows x 1024 cols
__global__ __launch_bounds__(256) void k_combine(
    const float* __restrict__ b_ih, const float* __restrict__ b_hh,
    const float* __restrict__ gbuf, float* __restrict__ X2T) {
  const int idx = blockIdx.x * 256 + threadIdx.x;
  const int r = idx >> 10;
  const int j = idx & 1023;
  const size_t SS = (size_t)64 * 4096;
  float sr  = b_ih[j] + b_hh[j];
  float sz  = b_ih[1024 + j] + b_hh[1024 + j];
  float inn = b_ih[2048 + j];
  float hn  = b_hh[2048 + j];
  #pragma unroll
  for (int s = 0; s < 8; s++) {
    const float* gs = gbuf + s * SS + (size_t)r * 4096;
    sr += gs[j];
    sz += gs[1024 + j];
    if (s < 4) inn += gs[2048 + j]; else hn += gs[3072 + j];
  }
  float rg = 1.f / (1.f + expf(-sr));
  float zg = 1.f / (1.f + expf(-sz));
  float n  = tanhf(inn + rg * hn);
  float hp = X2T[(size_t)(1024 + j) * 64 + r];
  float h  = (1.f - zg) * n + zg * hp;
  X2T[(size_t)(1024 + j) * 64 + r] = h;
}

// -------------------------------------------------------------------------
// FC GEMM + logits write + per-block argmax partials
// grid 250 (128 cols each), 256 threads (4 waves: 2 rowhalf x 2 colhalf)
__global__ __launch_bounds__(256) void k_fc(
    const float* __restrict__ fc_w, const float* __restrict__ fc_b,
    const float* __restrict__ hT, float* __restrict__ out,
    float* __restrict__ pv, int* __restrict__ pi, int t) {
  const int tid  = threadIdx.x;
  const int w    = __builtin_amdgcn_readfirstlane(tid >> 6);
  const int lane = tid & 63;
  const int r0   = (w >> 1) * 32;
  const int col  = blockIdx.x * 128 + (w & 1) * 64 + lane;
  const float* Bp = fc_w + (size_t)col * HID;
  float acc[32];
  #pragma unroll
  for (int i = 0; i < 32; i++) acc[i] = 0.f;
  for (int k = 0; k < HID; k += 4) {
    float4 b = *(const float4*)(Bp + k);
    #pragma unroll
    for (int kk = 0; kk < 4; kk++) {
      const float bk = (&b.x)[kk];
      const float* a = hT + (size_t)(k + kk) * 64 + r0;
      #pragma unroll
      for (int i = 0; i < 32; i++) acc[i] = fmaf(a[i], bk, acc[i]);
    }
  }
  const float bias = fc_b[col];
  #pragma unroll
  for (int i = 0; i < 32; i++) {
    float v = acc[i] + bias;
    acc[i] = v;
    out[((size_t)(r0 + i) * TLEN + t) * VOCAB + col] = v;
  }
  // per-row argmax over this block's 128 cols
  __shared__ float sv[2][64];
  __shared__ int   si[2][64];
  #pragma unroll 4
  for (int i = 0; i < 32; i++) {
    float v = acc[i]; int idx = col;
    #pragma unroll
    for (int d = 32; d > 0; d >>= 1) {
      float v2 = __shfl_xor(v, d);
      int i2   = __shfl_xor(idx, d);
      if (v2 > v || (v2 == v && i2 < idx)) { v = v2; idx = i2; }
    }
    if (lane == 0) { sv[w & 1][r0 + i] = v; si[w & 1][r0 + i] = idx; }
  }
  __syncthreads();
  if (tid < 64) {
    float v = sv[0][tid]; int idx = si[0][tid];
    float v2 = sv[1][tid]; int i2 = si[1][tid];
    if (v2 > v || (v2 == v && i2 < idx)) { v = v2; idx = i2; }
    pv[tid * FC_NCB + blockIdx.x] = v;
    pi[tid * FC_NCB + blockIdx.x] = idx;
  }
}

// -------------------------------------------------------------------------
extern "C" void kernel_launch(void* const* d_in, const int* in_sizes, int n_in,
                              void* d_out, int out_size, void* d_ws, size_t ws_size,
                              hipStream_t stream) {
  const float* enc  = (const float*)d_in[0];
  const int*   tt   = (const int*)d_in[1];
  const float* emb  = (const float*)d_in[2];
  const float* w_ih = (const float*)d_in[3];
  const float* w_hh = (const float*)d_in[4];
  const float* b_ih = (const float*)d_in[5];
  const float* b_hh = (const float*)d_in[6];
  const float* fc_w = (const float*)d_in[7];
  const float* fc_b = (const float*)d_in[8];
  float* out = (float*)d_out;
  float* ws  = (float*)d_ws;

  float* X2T  = ws + X2T_OFF;
  float* gbuf = ws + GBUF_OFF;
  float* pv   = ws + PV_OFF;
  int*   pi   = (int*)(ws + PI_OFF);

  for (int t = 0; t < TLEN; t++) {
    k_prep<<<64, 256, 0, stream>>>(enc, tt, emb, X2T, pv, pi, t);
    k_gates<<<256, 256, 0, stream>>>(w_ih, w_hh, X2T, gbuf);
    k_combine<<<256, 256, 0, stream>>>(b_ih, b_hh, gbuf, X2T);
    k_fc<<<FC_NCB, 256, 0, stream>>>(fc_w, fc_b, X2T + (size_t)HID * 64, out, pv, pi, t);
  }
}

// Round 2
// 16568.346 us; speedup vs baseline: 1.7444x; 1.7444x over previous
//
#include <hip/hip_runtime.h>
#include <cmath>

#define HID    1024
#define VOCAB  32000
#define TLEN   128
#define FC_NB  500               // 32000/64 col-blocks for FC argmax partials

typedef __attribute__((ext_vector_type(8))) short bf16x8;
typedef __attribute__((ext_vector_type(4))) float f32x4;

// ---------------- bf16 split helpers ----------------
__device__ __forceinline__ unsigned short bf_hi(float f) {
  unsigned u = __float_as_uint(f);
  return (unsigned short)((u + 0x7fffu + ((u >> 16) & 1u)) >> 16);
}
__device__ __forceinline__ float bf_f(unsigned short h) {
  return __uint_as_float(((unsigned)h) << 16);
}
__device__ __forceinline__ void split2(float f, unsigned short& hi, unsigned short& lo) {
  hi = bf_hi(f);
  lo = bf_hi(f - bf_f(hi));
}

// ================= new-path workspace layout (bytes) =================
#define OFF_FCW_HI 0ULL
#define OFF_FCW_LO 65536000ULL
#define OFF_WIH_HI 131072000ULL
#define OFF_WIH_LO 137363456ULL
#define OFF_WHH_HI 143654912ULL
#define OFF_WHH_LO 149946368ULL
#define OFF_GI     156237824ULL
#define OFF_GH     157024256ULL
#define OFF_H32    157810688ULL
#define OFF_XHI    158072832ULL
#define OFF_XLO    158203904ULL
#define OFF_HHI    158334976ULL
#define OFF_HLO    158466048ULL
#define OFF_PV     158597120ULL
#define OFF_PI     158725120ULL
#define WS_NEED    158853120ULL

// ---------------- one-time weight split ----------------
__global__ __launch_bounds__(256) void k_split(const float* __restrict__ src,
                                               unsigned short* __restrict__ hi,
                                               unsigned short* __restrict__ lo, int n4) {
  int i = blockIdx.x * 256 + threadIdx.x;
  const int stride = gridDim.x * 256;
  for (; i < n4; i += stride) {
    float4 v = ((const float4*)src)[i];
    ushort4 h, l;
    split2(v.x, h.x, l.x);
    split2(v.y, h.y, l.y);
    split2(v.z, h.z, l.z);
    split2(v.w, h.w, l.w);
    ((ushort4*)hi)[i] = h;
    ((ushort4*)lo)[i] = l;
  }
}

// ---------------- prep: argmax finalize + embedding gather/split ----------------
__global__ __launch_bounds__(256) void k_prep(
    const float* __restrict__ enc, const int* __restrict__ tt,
    const float* __restrict__ emb,
    const float* __restrict__ pv, const int* __restrict__ pi,
    unsigned short* __restrict__ xhi, unsigned short* __restrict__ xlo,
    float* __restrict__ h32, unsigned short* __restrict__ hhi,
    unsigned short* __restrict__ hlo, int t) {
  const int r = blockIdx.x;
  const int tid = threadIdx.x;
  __shared__ int s_tok;
  __shared__ float rv[256];
  __shared__ int ri[256];
  if (t == 0) {
    if (tid == 0) s_tok = tt[r * TLEN];
  } else {
    float v = -INFINITY; int ix = 0x7fffffff;
    if (tid < FC_NB) { v = pv[r * FC_NB + tid]; ix = pi[r * FC_NB + tid]; }
    int t2 = tid + 256;
    if (t2 < FC_NB) {
      float v2 = pv[r * FC_NB + t2]; int i2 = pi[r * FC_NB + t2];
      if (v2 > v || (v2 == v && i2 < ix)) { v = v2; ix = i2; }
    }
    rv[tid] = v; ri[tid] = ix;
    __syncthreads();
    for (int s = 128; s > 0; s >>= 1) {
      if (tid < s) {
        float v2 = rv[tid + s]; int i2 = ri[tid + s];
        if (v2 > rv[tid] || (v2 == rv[tid] && i2 < ri[tid])) { rv[tid] = v2; ri[tid] = i2; }
      }
      __syncthreads();
    }
    if (tid == 0) s_tok = ri[0];
  }
  __syncthreads();
  const int tok = s_tok;
  const float4* er = (const float4*)(emb + (size_t)tok * HID);
  ushort4* xh4 = (ushort4*)(xhi + (size_t)r * HID);
  ushort4* xl4 = (ushort4*)(xlo + (size_t)r * HID);
  for (int k4 = tid; k4 < HID / 4; k4 += 256) {
    float4 v = er[k4];
    ushort4 h, l;
    split2(v.x, h.x, l.x); split2(v.y, h.y, l.y);
    split2(v.z, h.z, l.z); split2(v.w, h.w, l.w);
    xh4[k4] = h; xl4[k4] = l;
  }
  if (t == 0) {
    const float4* hr = (const float4*)(enc + (size_t)r * HID);
    float4* h4o = (float4*)(h32 + (size_t)r * HID);
    ushort4* hh4 = (ushort4*)(hhi + (size_t)r * HID);
    ushort4* hl4 = (ushort4*)(hlo + (size_t)r * HID);
    for (int k4 = tid; k4 < HID / 4; k4 += 256) {
      float4 v = hr[k4];
      ushort4 h, l;
      split2(v.x, h.x, l.x); split2(v.y, h.y, l.y);
      split2(v.z, h.z, l.z); split2(v.w, h.w, l.w);
      h4o[k4] = v; hh4[k4] = h; hl4[k4] = l;
    }
  }
}

// ---------------- gates GEMM: gi = x@w_ih^T, gh = h@w_hh^T (split-bf16 MFMA) ----------------
// grid 96: blocks 0..47 -> ih, 48..95 -> hh; block = 4 waves x 16 cols = 64 cols
__global__ __launch_bounds__(256) void k_gates(
    const unsigned short* __restrict__ xhi, const unsigned short* __restrict__ xlo,
    const unsigned short* __restrict__ hhi, const unsigned short* __restrict__ hlo,
    const unsigned short* __restrict__ wihhi, const unsigned short* __restrict__ wihlo,
    const unsigned short* __restrict__ whhhi, const unsigned short* __restrict__ whhlo,
    float* __restrict__ gi, float* __restrict__ gh) {
  const int bid = blockIdx.x;
  const unsigned short *Ahi, *Alo, *Bhi, *Blo;
  float* C;
  int c0;
  if (bid < 48) { Ahi = xhi; Alo = xlo; Bhi = wihhi; Blo = wihlo; C = gi; c0 = bid * 64; }
  else          { Ahi = hhi; Alo = hlo; Bhi = whhhi; Blo = whhlo; C = gh; c0 = (bid - 48) * 64; }
  const int tid = threadIdx.x;
  const int w = tid >> 6;
  const int lane = tid & 63;
  const int n0 = c0 + w * 16;
  const int l15 = lane & 15;
  const int kg = (lane >> 4) * 8;
  const unsigned short* bph = Bhi + (size_t)(n0 + l15) * HID + kg;
  const unsigned short* bpl = Blo + (size_t)(n0 + l15) * HID + kg;
  const unsigned short* aph = Ahi + (size_t)l15 * HID + kg;
  const unsigned short* apl = Alo + (size_t)l15 * HID + kg;
  f32x4 acc[4] = {};
  for (int k0 = 0; k0 < HID; k0 += 32) {
    bf16x8 bh = *(const bf16x8*)(bph + k0);
    bf16x8 bl = *(const bf16x8*)(bpl + k0);
#pragma unroll
    for (int m = 0; m < 4; m++) {
      bf16x8 a1 = *(const bf16x8*)(aph + (size_t)m * 16 * HID + k0);
      bf16x8 a2 = *(const bf16x8*)(apl + (size_t)m * 16 * HID + k0);
      acc[m] = __builtin_amdgcn_mfma_f32_16x16x32_bf16(a1, bh, acc[m], 0, 0, 0);
      acc[m] = __builtin_amdgcn_mfma_f32_16x16x32_bf16(a2, bh, acc[m], 0, 0, 0);
      acc[m] = __builtin_amdgcn_mfma_f32_16x16x32_bf16(a1, bl, acc[m], 0, 0, 0);
    }
  }
  const int col = n0 + l15;
#pragma unroll
  for (int m = 0; m < 4; m++)
#pragma unroll
    for (int q = 0; q < 4; q++) {
      int row = m * 16 + (lane >> 4) * 4 + q;
      C[(size_t)row * 3072 + col] = acc[m][q];
    }
}

// ---------------- combine: GRU nonlinearity + h update + h split ----------------
__global__ __launch_bounds__(256) void k_combine(
    const float* __restrict__ gi, const float* __restrict__ gh,
    const float* __restrict__ b_ih, const float* __restrict__ b_hh,
    float* __restrict__ h32, unsigned short* __restrict__ hhi,
    unsigned short* __restrict__ hlo) {
  const int idx = blockIdx.x * 256 + threadIdx.x;   // 65536 = 64 x 1024
  const int r = idx >> 10;
  const int j = idx & 1023;
  const size_t gr = (size_t)r * 3072;
  float ir = gi[gr + j] + b_ih[j];
  float iz = gi[gr + 1024 + j] + b_ih[1024 + j];
  float inn = gi[gr + 2048 + j] + b_ih[2048 + j];
  float hr = gh[gr + j] + b_hh[j];
  float hz = gh[gr + 1024 + j] + b_hh[1024 + j];
  float hn = gh[gr + 2048 + j] + b_hh[2048 + j];
  float rg = 1.f / (1.f + expf(-(ir + hr)));
  float zg = 1.f / (1.f + expf(-(iz + hz)));
  float n = tanhf(inn + rg * hn);
  float hp = h32[(size_t)r * HID + j];
  float h = (1.f - zg) * n + zg * hp;
  h32[(size_t)r * HID + j] = h;
  unsigned short hi, lo;
  split2(h, hi, lo);
  hhi[(size_t)r * HID + j] = hi;
  hlo[(size_t)r * HID + j] = lo;
}

// ---------------- FC GEMM (split-bf16 MFMA) + logits + argmax partials ----------------
// grid 500: block = 4 waves x 16 cols = 64 cols
__global__ __launch_bounds__(256) void k_fc(
    const unsigned short* __restrict__ ahi, const unsigned short* __restrict__ alo,
    const unsigned short* __restrict__ fwhi, const unsigned short* __restrict__ fwlo,
    const float* __restrict__ fc_b, float* __restrict__ out,
    float* __restrict__ pv, int* __restrict__ pi, int t) {
  const int bid = blockIdx.x;
  const int tid = threadIdx.x;
  const int w = tid >> 6;
  const int lane = tid & 63;
  const int n0 = bid * 64 + w * 16;
  const int l15 = lane & 15;
  const int kg = (lane >> 4) * 8;
  const unsigned short* bph = fwhi + (size_t)(n0 + l15) * HID + kg;
  const unsigned short* bpl = fwlo + (size_t)(n0 + l15) * HID + kg;
  const unsigned short* aph = ahi + (size_t)l15 * HID + kg;
  const unsigned short* apl = alo + (size_t)l15 * HID + kg;
  f32x4 acc[4] = {};
  for (int k0 = 0; k0 < HID; k0 += 32) {
    bf16x8 bh = *(const bf16x8*)(bph + k0);
    bf16x8 bl = *(const bf16x8*)(bpl + k0);
#pragma unroll
    for (int m = 0; m < 4; m++) {
      bf16x8 a1 = *(const bf16x8*)(aph + (size_t)m * 16 * HID + k0);
      bf16x8 a2 = *(const bf16x8*)(apl + (size_t)m * 16 * HID + k0);
      acc[m] = __builtin_amdgcn_mfma_f32_16x16x32_bf16(a1, bh, acc[m], 0, 0, 0);
      acc[m] = __builtin_amdgcn_mfma_f32_16x16x32_bf16(a2, bh, acc[m], 0, 0, 0);
      acc[m] = __builtin_amdgcn_mfma_f32_16x16x32_bf16(a1, bl, acc[m], 0, 0, 0);
    }
  }
  const int col = n0 + l15;
  const float bias = fc_b[col];
  __shared__ float svv[4][64];
  __shared__ int svi[4][64];
#pragma unroll
  for (int m = 0; m < 4; m++)
#pragma unroll
    for (int q = 0; q < 4; q++) {
      float v = acc[m][q] + bias;
      int row = m * 16 + (lane >> 4) * 4 + q;
      out[((size_t)row * TLEN + t) * VOCAB + col] = v;
      float bv = v; int bi = col;
#pragma unroll
      for (int d = 1; d < 16; d <<= 1) {
        float ov = __shfl_xor(bv, d);
        int oi = __shfl_xor(bi, d);
        if (ov > bv || (ov == bv && oi < bi)) { bv = ov; bi = oi; }
      }
      if (l15 == 0) { svv[w][row] = bv; svi[w][row] = bi; }
    }
  __syncthreads();
  if (tid < 64) {
    float v = svv[0][tid]; int ix = svi[0][tid];
#pragma unroll
    for (int ww = 1; ww < 4; ww++) {
      float v2 = svv[ww][tid]; int i2 = svi[ww][tid];
      if (v2 > v || (v2 == v && i2 < ix)) { v = v2; ix = i2; }
    }
    pv[(size_t)tid * FC_NB + bid] = v;
    pi[(size_t)tid * FC_NB + bid] = ix;
  }
}

// ======================= OLD fp32 fallback path (round-1, known-good) =======================
#define O_FC_NCB 250
#define O_X2T_OFF  0
#define O_GBUF_OFF (2048*64)
#define O_PV_OFF   (O_GBUF_OFF + 8*64*4096)
#define O_PI_OFF   (O_PV_OFF + 64*O_FC_NCB)

__global__ __launch_bounds__(256) void o_prep(
    const float* __restrict__ enc, const int* __restrict__ tt,
    const float* __restrict__ emb, float* __restrict__ X2T,
    const float* __restrict__ pv, const int* __restrict__ pi, int t) {
  const int r = blockIdx.x;
  const int tid = threadIdx.x;
  __shared__ int s_tok;
  __shared__ float red_v[256];
  __shared__ int red_i[256];
  if (t == 0) {
    if (tid == 0) s_tok = tt[r * TLEN];
  } else {
    float v = -INFINITY; int idx = 0x7fffffff;
    if (tid < O_FC_NCB) { v = pv[r * O_FC_NCB + tid]; idx = pi[r * O_FC_NCB + tid]; }
    red_v[tid] = v; red_i[tid] = idx;
    __syncthreads();
    for (int s = 128; s > 0; s >>= 1) {
      if (tid < s) {
        float v2 = red_v[tid + s]; int i2 = red_i[tid + s];
        if (v2 > red_v[tid] || (v2 == red_v[tid] && i2 < red_i[tid])) {
          red_v[tid] = v2; red_i[tid] = i2;
        }
      }
      __syncthreads();
    }
    if (tid == 0) s_tok = red_i[0];
  }
  __syncthreads();
  const int tok = s_tok;
  for (int k = tid; k < HID; k += 256)
    X2T[(size_t)k * 64 + r] = emb[(size_t)tok * HID + k];
  if (t == 0) {
    for (int k = tid; k < HID; k += 256)
      X2T[(size_t)(HID + k) * 64 + r] = enc[r * HID + k];
  }
}

__global__ __launch_bounds__(256) void o_gates(
    const float* __restrict__ w_ih, const float* __restrict__ w_hh,
    const float* __restrict__ X2T, float* __restrict__ gbuf) {
  const int cb = blockIdx.x & 31;
  const int s  = blockIdx.x >> 5;
  const int g  = cb >> 3;
  if (g == 2 && s >= 4) return;
  if (g == 3 && s < 4) return;
  const int tid  = threadIdx.x;
  const int w    = __builtin_amdgcn_readfirstlane(tid >> 6);
  const int lane = tid & 63;
  const int r0   = (w >> 1) * 32;
  const int cc   = cb * 128 + (w & 1) * 64 + lane;
  const int j    = cc & 1023;
  const float* Bmat; int kk0;
  if (s < 4) { Bmat = w_ih; kk0 = s * 256; }
  else       { Bmat = w_hh; kk0 = (s - 4) * 256; }
  int brow;
  if (g == 0) brow = j;
  else if (g == 1) brow = 1024 + j;
  else brow = 2048 + j;
  const float* Bp = Bmat + (size_t)brow * HID + kk0;
  const float* Ap = X2T + (size_t)(s * 256) * 64 + r0;
  float acc[32];
#pragma unroll
  for (int i = 0; i < 32; i++) acc[i] = 0.f;
  for (int k = 0; k < 256; k += 4) {
    float4 b = *(const float4*)(Bp + k);
#pragma unroll
    for (int kk = 0; kk < 4; kk++) {
      const float bk = (&b.x)[kk];
      const float* a = Ap + (size_t)(k + kk) * 64;
#pragma unroll
      for (int i = 0; i < 32; i++) acc[i] = fmaf(a[i], bk, acc[i]);
    }
  }
  float* C = gbuf + (size_t)s * (64 * 4096) + cc;
#pragma unroll
  for (int i = 0; i < 32; i++) C[(size_t)(r0 + i) * 4096] = acc[i];
}

__global__ __launch_bounds__(256) void o_combine(
    const float* __restrict__ b_ih, const float* __restrict__ b_hh,
    const float* __restrict__ gbuf, float* __restrict__ X2T) {
  const int idx = blockIdx.x * 256 + threadIdx.x;
  const int r = idx >> 10;
  const int j = idx & 1023;
  const size_t SS = (size_t)64 * 4096;
  float sr  = b_ih[j] + b_hh[j];
  float sz  = b_ih[1024 + j] + b_hh[1024 + j];
  float inn = b_ih[2048 + j];
  float hn  = b_hh[2048 + j];
#pragma unroll
  for (int s = 0; s < 8; s++) {
    const float* gs = gbuf + s * SS + (size_t)r * 4096;
    sr += gs[j];
    sz += gs[1024 + j];
    if (s < 4) inn += gs[2048 + j]; else hn += gs[3072 + j];
  }
  float rg = 1.f / (1.f + expf(-sr));
  float zg = 1.f / (1.f + expf(-sz));
  float n  = tanhf(inn + rg * hn);
  float hp = X2T[(size_t)(1024 + j) * 64 + r];
  float h  = (1.f - zg) * n + zg * hp;
  X2T[(size_t)(1024 + j) * 64 + r] = h;
}

__global__ __launch_bounds__(256) void o_fc(
    const float* __restrict__ fc_w, const float* __restrict__ fc_b,
    const float* __restrict__ hT, float* __restrict__ out,
    float* __restrict__ pv, int* __restrict__ pi, int t) {
  const int tid  = threadIdx.x;
  const int w    = __builtin_amdgcn_readfirstlane(tid >> 6);
  const int lane = tid & 63;
  const int r0   = (w >> 1) * 32;
  const int col  = blockIdx.x * 128 + (w & 1) * 64 + lane;
  const float* Bp = fc_w + (size_t)col * HID;
  float acc[32];
#pragma unroll
  for (int i = 0; i < 32; i++) acc[i] = 0.f;
  for (int k = 0; k < HID; k += 4) {
    float4 b = *(const float4*)(Bp + k);
#pragma unroll
    for (int kk = 0; kk < 4; kk++) {
      const float bk = (&b.x)[kk];
      const float* a = hT + (size_t)(k + kk) * 64 + r0;
#pragma unroll
      for (int i = 0; i < 32; i++) acc[i] = fmaf(a[i], bk, acc[i]);
    }
  }
  const float bias = fc_b[col];
#pragma unroll
  for (int i = 0; i < 32; i++) {
    float v = acc[i] + bias;
    acc[i] = v;
    out[((size_t)(r0 + i) * TLEN + t) * VOCAB + col] = v;
  }
  __shared__ float sv[2][64];
  __shared__ int   si[2][64];
#pragma unroll 4
  for (int i = 0; i < 32; i++) {
    float v = acc[i]; int idx = col;
#pragma unroll
    for (int d = 32; d > 0; d >>= 1) {
      float v2 = __shfl_xor(v, d);
      int i2   = __shfl_xor(idx, d);
      if (v2 > v || (v2 == v && i2 < idx)) { v = v2; idx = i2; }
    }
    if (lane == 0) { sv[w & 1][r0 + i] = v; si[w & 1][r0 + i] = idx; }
  }
  __syncthreads();
  if (tid < 64) {
    float v = sv[0][tid]; int idx = si[0][tid];
    float v2 = sv[1][tid]; int i2 = si[1][tid];
    if (v2 > v || (v2 == v && i2 < idx)) { v = v2; idx = i2; }
    pv[tid * O_FC_NCB + blockIdx.x] = v;
    pi[tid * O_FC_NCB + blockIdx.x] = idx;
  }
}

// =======================================================================
extern "C" void kernel_launch(void* const* d_in, const int* in_sizes, int n_in,
                              void* d_out, int out_size, void* d_ws, size_t ws_size,
                              hipStream_t stream) {
  const float* enc  = (const float*)d_in[0];
  const int*   tt   = (const int*)d_in[1];
  const float* emb  = (const float*)d_in[2];
  const float* w_ih = (const float*)d_in[3];
  const float* w_hh = (const float*)d_in[4];
  const float* b_ih = (const float*)d_in[5];
  const float* b_hh = (const float*)d_in[6];
  const float* fc_w = (const float*)d_in[7];
  const float* fc_b = (const float*)d_in[8];
  float* out = (float*)d_out;

  if (ws_size >= WS_NEED) {
    char* ws = (char*)d_ws;
    unsigned short* fcw_hi = (unsigned short*)(ws + OFF_FCW_HI);
    unsigned short* fcw_lo = (unsigned short*)(ws + OFF_FCW_LO);
    unsigned short* wih_hi = (unsigned short*)(ws + OFF_WIH_HI);
    unsigned short* wih_lo = (unsigned short*)(ws + OFF_WIH_LO);
    unsigned short* whh_hi = (unsigned short*)(ws + OFF_WHH_HI);
    unsigned short* whh_lo = (unsigned short*)(ws + OFF_WHH_LO);
    float* gi  = (float*)(ws + OFF_GI);
    float* gh  = (float*)(ws + OFF_GH);
    float* h32 = (float*)(ws + OFF_H32);
    unsigned short* xhi = (unsigned short*)(ws + OFF_XHI);
    unsigned short* xlo = (unsigned short*)(ws + OFF_XLO);
    unsigned short* hhi = (unsigned short*)(ws + OFF_HHI);
    unsigned short* hlo = (unsigned short*)(ws + OFF_HLO);
    float* pv = (float*)(ws + OFF_PV);
    int*   pi = (int*)(ws + OFF_PI);

    k_split<<<4096, 256, 0, stream>>>(fc_w, fcw_hi, fcw_lo, VOCAB * HID / 4);
    k_split<<<1536, 256, 0, stream>>>(w_ih, wih_hi, wih_lo, 3 * HID * HID / 4);
    k_split<<<1536, 256, 0, stream>>>(w_hh, whh_hi, whh_lo, 3 * HID * HID / 4);

    for (int t = 0; t < TLEN; t++) {
      k_prep<<<64, 256, 0, stream>>>(enc, tt, emb, pv, pi, xhi, xlo, h32, hhi, hlo, t);
      k_gates<<<96, 256, 0, stream>>>(xhi, xlo, hhi, hlo, wih_hi, wih_lo, whh_hi, whh_lo, gi, gh);
      k_combine<<<256, 256, 0, stream>>>(gi, gh, b_ih, b_hh, h32, hhi, hlo);
      k_fc<<<FC_NB, 256, 0, stream>>>(hhi, hlo, fcw_hi, fcw_lo, fc_b, out, pv, pi, t);
    }
  } else {
    float* ws = (float*)d_ws;
    float* X2T  = ws + O_X2T_OFF;
    float* gbuf = ws + O_GBUF_OFF;
    float* pv   = ws + O_PV_OFF;
    int*   pi   = (int*)(ws + O_PI_OFF);
    for (int t = 0; t < TLEN; t++) {
      o_prep<<<64, 256, 0, stream>>>(enc, tt, emb, X2T, pv, pi, t);
      o_gates<<<256, 256, 0, stream>>>(w_ih, w_hh, X2T, gbuf);
      o_combine<<<256, 256, 0, stream>>>(b_ih, b_hh, gbuf, X2T);
      o_fc<<<O_FC_NCB, 256, 0, stream>>>(fc_w, fc_b, X2T + (size_t)HID * 64, out, pv, pi, t);
    }
  }
}